// Round 1
// baseline (772.182 us; speedup 1.0000x reference)
//
#include <hip/hip_runtime.h>

#define NN 100000   // nodes
#define NE 1600000  // edges
#define NR 8        // relations
#define DD 128      // feature dim
#define NKEY (NN * NR)               // 800000 (dst,rel) keys
#define NBLK ((NKEY + 1023) / 1024)  // 782 scan blocks
#define RSTRIDE 580                  // sAgg row stride in dwords (4*odd -> clean banks)

typedef __attribute__((ext_vector_type(8))) short short8;
typedef __attribute__((ext_vector_type(4))) float f32x4;

__device__ __forceinline__ float bf2f(unsigned short u) {
  union { unsigned int i; float f; } c; c.i = ((unsigned int)u) << 16; return c.f;
}
__device__ __forceinline__ unsigned short f2bf(float f) {
  union { float f; unsigned int i; } c; c.f = f;
  unsigned int u = c.i;
  return (unsigned short)((u + 0x7FFFu + ((u >> 16) & 1u)) >> 16);  // RNE
}

// ---- preprocessing ----------------------------------------------------------

__global__ __launch_bounds__(256) void k_cast(
    const float* __restrict__ x, unsigned short* __restrict__ xb) {
  int i = blockIdx.x * 256 + threadIdx.x;          // over N*D/4
  if (i < NN * DD / 4) {
    float4 f = ((const float4*)x)[i];
    ushort4 u;
    u.x = f2bf(f.x); u.y = f2bf(f.y); u.z = f2bf(f.z); u.w = f2bf(f.w);
    ((ushort4*)xb)[i] = u;
  }
}

// wbf[layer][rb][n][k] = W[rb][k][n]  (rb==8 -> root), bf16
__global__ __launch_bounds__(256) void k_wtrans(
    const float* __restrict__ W1, const float* __restrict__ root1,
    const float* __restrict__ W2, const float* __restrict__ root2,
    unsigned short* __restrict__ wbf) {
  int idx = blockIdx.x * 256 + threadIdx.x;        // 2*9*16384 total
  int layer = idx / (9 * 16384);
  int rem = idx % (9 * 16384);
  int r = rem / 16384;
  int nk = rem % 16384;
  int n = nk >> 7, k = nk & 127;
  float v;
  if (r < 8) v = (layer ? W2 : W1)[r * 16384 + k * 128 + n];
  else       v = (layer ? root2 : root1)[k * 128 + n];
  wbf[idx] = f2bf(v);
}

__global__ __launch_bounds__(256) void k_zero(int* __restrict__ p, int n) {
  int i = blockIdx.x * 256 + threadIdx.x;
  if (i < n) p[i] = 0;
}

__global__ __launch_bounds__(256) void k_count(
    const int* __restrict__ ei, const int* __restrict__ et, int* __restrict__ cnt) {
  int e = blockIdx.x * 256 + threadIdx.x;
  if (e < NE) {
    int dst = ei[NE + e];
    int r = et[e];
    atomicAdd(&cnt[dst * NR + r], 1);
  }
}

// hierarchical exclusive scan over NKEY elements — shfl-based (3 barriers,
// replaces the 20-barrier O(n log n) LDS ladder)
__global__ __launch_bounds__(1024) void k_scan1(
    const int* __restrict__ cnt, int* __restrict__ offs, int* __restrict__ bsum) {
  __shared__ int sw[16];
  int t = threadIdx.x, b = blockIdx.x;
  int lane = t & 63, wid = t >> 6;
  int i = b * 1024 + t;
  int v = (i < NKEY) ? cnt[i] : 0;
  int x = v;
#pragma unroll
  for (int o = 1; o < 64; o <<= 1) {               // inclusive wave scan
    int y = __shfl_up(x, o);
    if (lane >= o) x += y;
  }
  if (lane == 63) sw[wid] = x;
  __syncthreads();
  if (wid == 0) {
    int s = (lane < 16) ? sw[lane] : 0;
#pragma unroll
    for (int o = 1; o < 16; o <<= 1) {
      int y = __shfl_up(s, o);
      if (lane >= o) s += y;
    }
    if (lane < 16) sw[lane] = s;                   // inclusive wave totals
  }
  __syncthreads();
  int base = (wid > 0) ? sw[wid - 1] : 0;
  if (i < NKEY) offs[i] = base + x - v;            // block-local exclusive
  if (t == 1023) bsum[b] = base + x;               // block total
}

__global__ __launch_bounds__(1024) void k_scan2(int* __restrict__ bsum) {
  __shared__ int sw[16];
  int t = threadIdx.x;
  int lane = t & 63, wid = t >> 6;
  int v = (t < NBLK) ? bsum[t] : 0;
  int x = v;
#pragma unroll
  for (int o = 1; o < 64; o <<= 1) {
    int y = __shfl_up(x, o);
    if (lane >= o) x += y;
  }
  if (lane == 63) sw[wid] = x;
  __syncthreads();
  if (wid == 0) {
    int s = (lane < 16) ? sw[lane] : 0;
#pragma unroll
    for (int o = 1; o < 16; o <<= 1) {
      int y = __shfl_up(s, o);
      if (lane >= o) s += y;
    }
    if (lane < 16) sw[lane] = s;
  }
  __syncthreads();
  int base = (wid > 0) ? sw[wid - 1] : 0;
  if (t < NBLK) bsum[t] = base + x - v;            // exclusive block bases
}

__global__ __launch_bounds__(256) void k_scan3(
    int* __restrict__ offs, const int* __restrict__ bsum, int* __restrict__ csr) {
  int i = blockIdx.x * 256 + threadIdx.x;
  if (i < NKEY) offs[i] += bsum[i >> 10];
  if (i == 0) offs[NKEY] = NE;                     // total is always NE
  if (i < 128) csr[NE + i] = 0;                    // zero pad -> no src clamp in k_fused
}

// scatter edges; reuses cnt as the fill counter (atomicSub), so no `fill` buf
__global__ __launch_bounds__(256) void k_csr(
    const int* __restrict__ ei, const int* __restrict__ et,
    const int* __restrict__ offs, int* __restrict__ cnt, int* __restrict__ csr) {
  int e = blockIdx.x * 256 + threadIdx.x;
  if (e < NE) {
    int src = ei[e];
    int key = ei[NE + e] * NR + et[e];
    int old = atomicSub(&cnt[key], 1);
    csr[offs[key] + old - 1] = src;
  }
}

// ---- fused per-layer kernel -------------------------------------------------
// Block (512 thr, 8 waves) owns 16 dst nodes = 128 (dst,rel) keys; LDS stays
// 37120 B so 4 blocks/CU x 512 thr = 2048 thr = 32 waves/CU (100% occupancy;
// the 256-thr version was LDS-shape-capped at 50%, and the random-gather edge
// phase is latency-bound). Wave w owns keys 16w..16w+15 (a contiguous csr
// range): streams edges with an 8-deep software-pipelined row gather. Gather
// srcs are moved to SGPRs via readlane so each gather is a single saddr-form
// global_load_dword (SALU base math, no per-lane clamp — csr pad is zeroed),
// and key-transition control flow is wave-uniform scalar branches.
// MFMA phase: wave w computes output cols 16w..16w+15 over all 9 matrices.
template <int RELU, int OUTBF>
__global__ __launch_bounds__(512, 8) void k_fused(
    const unsigned short* __restrict__ xb,   // [N][128] bf16
    const unsigned short* __restrict__ wl,   // [9][128][128] n-major bf16
    const int* __restrict__ offs, const int* __restrict__ csr,
    const float* __restrict__ bias, void* __restrict__ outp) {
  __shared__ unsigned int sAgg32[16 * RSTRIDE];    // [16 nodes][9*128+8] bf16, 37120 B
  const unsigned short* sAggH = (const unsigned short*)sAgg32;

  const int tid = threadIdx.x;
  const int w = tid >> 6;                          // 8 waves
  const int lane = tid & 63;
  const int m = lane & 15, q = lane >> 4;
  const int n0 = blockIdx.x * 16;
  const int k0 = n0 * NR;

  // this wave's 17 key offsets, one per lane (lane 0..16)
  int oidx = k0 + 16 * w + lane;
  if (oidx > NKEY) oidx = NKEY;
  const int offv = offs[oidx];
  const int p0 = __builtin_amdgcn_readlane(offv, 0);
  const int p1 = __builtin_amdgcn_readlane(offv, 16);

  // root row for this wave's 2 nodes: xb -> sAgg slot 8 (bf16 passthrough)
#pragma unroll
  for (int i = 0; i < 2; i++) {
    int node = 2 * w + i;
    unsigned int v = *(const unsigned int*)(xb + (size_t)(n0 + node) * DD + 2 * lane);
    sAgg32[node * RSTRIDE + 8 * 64 + lane] = v;
  }

  // ---- edge phase ----
  int kloc = 0;
  int kbeg = p0;
  int kend = __builtin_amdgcn_readlane(offv, 1);
  float ax = 0.f, ay = 0.f;

  int wbase = p0;                                  // csr window [wbase, wbase+64)
  int pv = csr[wbase + lane];                      // csr padded +128 zeroed ints
  ushort2 vb[8];
#pragma unroll
  for (int j = 0; j < 8; j++) {
    unsigned s = (unsigned)__builtin_amdgcn_readlane(pv, j);
    vb[j] = *(const ushort2*)(xb + (size_t)s * DD + 2 * lane);
  }

  for (int base = p0; base < p1; base += 8) {
    const int nbase = base + 8;
    if (((nbase - p0) & 63) == 0) {                // slide csr window
      wbase = nbase;
      pv = csr[wbase + lane];
    }
    ushort2 nv[8];
#pragma unroll
    for (int j = 0; j < 8; j++) {                  // issue next 8 gathers (SGPR base)
      unsigned s = (unsigned)__builtin_amdgcn_readlane(pv, nbase - wbase + j);
      nv[j] = *(const ushort2*)(xb + (size_t)s * DD + 2 * lane);
    }
#pragma unroll
    for (int j = 0; j < 8; j++) {                  // consume current 8
      if (base + j < p1) {
        while (base + j >= kend) {                 // key transition(s): flush
          float nm = __builtin_amdgcn_rcpf(fmaxf((float)(kend - kbeg), 1.f));
          unsigned lo = f2bf(ax * nm), hi = f2bf(ay * nm);
          int node = 2 * w + (kloc >> 3);
          sAgg32[node * RSTRIDE + (kloc & 7) * 64 + lane] = lo | (hi << 16);
          ax = 0.f; ay = 0.f;
          kloc++;
          kbeg = kend;
          kend = __builtin_amdgcn_readlane(offv, kloc + 1);
        }
        ax += bf2f(vb[j].x);
        ay += bf2f(vb[j].y);
      }
    }
#pragma unroll
    for (int j = 0; j < 8; j++) vb[j] = nv[j];
  }
  // drain remaining keys (incl. empty)
  while (kloc < 16) {
    float nm = __builtin_amdgcn_rcpf(fmaxf((float)(kend - kbeg), 1.f));
    unsigned lo = f2bf(ax * nm), hi = f2bf(ay * nm);
    int node = 2 * w + (kloc >> 3);
    sAgg32[node * RSTRIDE + (kloc & 7) * 64 + lane] = lo | (hi << 16);
    ax = 0.f; ay = 0.f;
    kloc++;
    kbeg = kend;
    kend = (kloc < 16) ? __builtin_amdgcn_readlane(offv, kloc + 1) : kend;
  }
  __syncthreads();

  // ---- MFMA phase: wave w -> output cols 16w..16w+15, all 9 matrices ----
  f32x4 acc = {0.f, 0.f, 0.f, 0.f};
  for (int mat = 0; mat < 9; mat++) {
    short8 a[4];
#pragma unroll
    for (int ks = 0; ks < 4; ks++)
      a[ks] = *(const short8*)(sAggH + m * (2 * RSTRIDE) + mat * 128 + ks * 32 + q * 8);
    const unsigned short* wr = wl + mat * DD * DD;
#pragma unroll
    for (int ks = 0; ks < 4; ks++) {
      short8 b = *(const short8*)(wr + (w * 16 + m) * DD + ks * 32 + q * 8);
      acc = __builtin_amdgcn_mfma_f32_16x16x32_bf16(a[ks], b, acc, 0, 0, 0);
    }
  }

  // epilogue: C/D row = q*4+i, col = w*16+m
  {
    const int c0 = w * 16 + m;
    const float bv = bias[c0];
#pragma unroll
    for (int i = 0; i < 4; i++) {
      int row = n0 + q * 4 + i;
      float v = acc[i] + bv;
      if (RELU) v = fmaxf(v, 0.f);
      if (OUTBF) {
        ((unsigned short*)outp)[(size_t)row * DD + c0] = f2bf(v);
      } else {
        ((float*)outp)[(size_t)row * DD + c0] = v;
      }
    }
  }
}

// ---- launch -----------------------------------------------------------------

extern "C" void kernel_launch(void* const* d_in, const int* in_sizes, int n_in,
                              void* d_out, int out_size, void* d_ws, size_t ws_size,
                              hipStream_t stream) {
  const float* x     = (const float*)d_in[0];
  const int*   ei    = (const int*)d_in[1];
  const int*   et    = (const int*)d_in[2];
  const float* W1    = (const float*)d_in[3];
  const float* root1 = (const float*)d_in[4];
  const float* b1    = (const float*)d_in[5];
  const float* W2    = (const float*)d_in[6];
  const float* root2 = (const float*)d_in[7];
  const float* b2    = (const float*)d_in[8];
  float* out = (float*)d_out;

  char* p = (char*)d_ws;
  unsigned short* xb1 = (unsigned short*)p; p += (size_t)NN * DD * 2;   // 25.6 MB
  unsigned short* xb2 = (unsigned short*)p; p += (size_t)NN * DD * 2;   // 25.6 MB
  unsigned short* wbf = (unsigned short*)p; p += (size_t)2 * 9 * DD * DD * 2;
  int* cnt  = (int*)p; p += (size_t)NKEY * 4;                           // 3.2 MB
  int* offs = (int*)p; p += (size_t)(NKEY + 16) * 4;                    // 3.2 MB
  int* bsum = (int*)p; p += (size_t)800 * 4;                            // NBLK=782
  int* csr  = (int*)p; p += (size_t)(NE + 128) * 4;                     // 6.4 MB (+zeroed pad)
  // total ~= 64 MB

  k_cast<<<(NN * DD / 4 + 255) / 256, 256, 0, stream>>>(x, xb1);
  k_wtrans<<<(2 * 9 * 16384) / 256, 256, 0, stream>>>(W1, root1, W2, root2, wbf);
  k_zero<<<(NKEY + 255) / 256, 256, 0, stream>>>(cnt, NKEY);
  k_count<<<(NE + 255) / 256, 256, 0, stream>>>(ei, et, cnt);
  k_scan1<<<NBLK, 1024, 0, stream>>>(cnt, offs, bsum);
  k_scan2<<<1, 1024, 0, stream>>>(bsum);
  k_scan3<<<(NKEY + 255) / 256, 256, 0, stream>>>(offs, bsum, csr);
  k_csr<<<(NE + 255) / 256, 256, 0, stream>>>(ei, et, offs, cnt, csr);

  dim3 fgrid(NN / 16);   // 6250
  k_fused<1, 1><<<fgrid, 512, 0, stream>>>(xb1, wbf, offs, csr, b1, (void*)xb2);
  k_fused<0, 0><<<fgrid, 512, 0, stream>>>(xb2, wbf + 9 * DD * DD, offs, csr, b2, (void*)out);
}

// Round 3
// 596.792 us; speedup vs baseline: 1.2939x; 1.2939x over previous
//
#include <hip/hip_runtime.h>

#define NN 100000   // nodes
#define NE 1600000  // edges
#define NR 8        // relations
#define DD 128      // feature dim
#define NKEY (NN * NR)               // 800000 (dst,rel) keys
#define NBLK ((NKEY + 1023) / 1024)  // 782 scan blocks
#define RSTRIDE 580                  // sAgg row stride in dwords (4*odd -> clean banks)

typedef __attribute__((ext_vector_type(8))) short short8;
typedef __attribute__((ext_vector_type(4))) float f32x4;

__device__ __forceinline__ float bf2f(unsigned short u) {
  union { unsigned int i; float f; } c; c.i = ((unsigned int)u) << 16; return c.f;
}
__device__ __forceinline__ unsigned short f2bf(float f) {
  union { float f; unsigned int i; } c; c.f = f;
  unsigned int u = c.i;
  return (unsigned short)((u + 0x7FFFu + ((u >> 16) & 1u)) >> 16);  // RNE
}

// ---- preprocessing ----------------------------------------------------------

__global__ __launch_bounds__(256) void k_cast(
    const float* __restrict__ x, unsigned short* __restrict__ xb) {
  int i = blockIdx.x * 256 + threadIdx.x;          // over N*D/4
  if (i < NN * DD / 4) {
    float4 f = ((const float4*)x)[i];
    ushort4 u;
    u.x = f2bf(f.x); u.y = f2bf(f.y); u.z = f2bf(f.z); u.w = f2bf(f.w);
    ((ushort4*)xb)[i] = u;
  }
}

// wbf[layer][rb][n][k] = W[rb][k][n]  (rb==8 -> root), bf16
__global__ __launch_bounds__(256) void k_wtrans(
    const float* __restrict__ W1, const float* __restrict__ root1,
    const float* __restrict__ W2, const float* __restrict__ root2,
    unsigned short* __restrict__ wbf) {
  int idx = blockIdx.x * 256 + threadIdx.x;        // 2*9*16384 total
  int layer = idx / (9 * 16384);
  int rem = idx % (9 * 16384);
  int r = rem / 16384;
  int nk = rem % 16384;
  int n = nk >> 7, k = nk & 127;
  float v;
  if (r < 8) v = (layer ? W2 : W1)[r * 16384 + k * 128 + n];
  else       v = (layer ? root2 : root1)[k * 128 + n];
  wbf[idx] = f2bf(v);
}

__global__ __launch_bounds__(256) void k_zero(int* __restrict__ p, int n) {
  int i = blockIdx.x * 256 + threadIdx.x;
  if (i < n) p[i] = 0;
}

__global__ __launch_bounds__(256) void k_count(
    const int* __restrict__ ei, const int* __restrict__ et, int* __restrict__ cnt) {
  int e = blockIdx.x * 256 + threadIdx.x;
  if (e < NE) {
    int dst = ei[NE + e];
    int r = et[e];
    atomicAdd(&cnt[dst * NR + r], 1);
  }
}

// hierarchical exclusive scan over NKEY elements — shfl-based
__global__ __launch_bounds__(1024) void k_scan1(
    const int* __restrict__ cnt, int* __restrict__ offs, int* __restrict__ bsum) {
  __shared__ int sw[16];
  int t = threadIdx.x, b = blockIdx.x;
  int lane = t & 63, wid = t >> 6;
  int i = b * 1024 + t;
  int v = (i < NKEY) ? cnt[i] : 0;
  int x = v;
#pragma unroll
  for (int o = 1; o < 64; o <<= 1) {
    int y = __shfl_up(x, o);
    if (lane >= o) x += y;
  }
  if (lane == 63) sw[wid] = x;
  __syncthreads();
  if (wid == 0) {
    int s = (lane < 16) ? sw[lane] : 0;
#pragma unroll
    for (int o = 1; o < 16; o <<= 1) {
      int y = __shfl_up(s, o);
      if (lane >= o) s += y;
    }
    if (lane < 16) sw[lane] = s;
  }
  __syncthreads();
  int base = (wid > 0) ? sw[wid - 1] : 0;
  if (i < NKEY) offs[i] = base + x - v;
  if (t == 1023) bsum[b] = base + x;
}

__global__ __launch_bounds__(1024) void k_scan2(int* __restrict__ bsum) {
  __shared__ int sw[16];
  int t = threadIdx.x;
  int lane = t & 63, wid = t >> 6;
  int v = (t < NBLK) ? bsum[t] : 0;
  int x = v;
#pragma unroll
  for (int o = 1; o < 64; o <<= 1) {
    int y = __shfl_up(x, o);
    if (lane >= o) x += y;
  }
  if (lane == 63) sw[wid] = x;
  __syncthreads();
  if (wid == 0) {
    int s = (lane < 16) ? sw[lane] : 0;
#pragma unroll
    for (int o = 1; o < 16; o <<= 1) {
      int y = __shfl_up(s, o);
      if (lane >= o) s += y;
    }
    if (lane < 16) sw[lane] = s;
  }
  __syncthreads();
  int base = (wid > 0) ? sw[wid - 1] : 0;
  if (t < NBLK) bsum[t] = base + x - v;
}

__global__ __launch_bounds__(256) void k_scan3(
    int* __restrict__ offs, const int* __restrict__ bsum, int* __restrict__ csr) {
  int i = blockIdx.x * 256 + threadIdx.x;
  if (i < NKEY) offs[i] += bsum[i >> 10];
  if (i == 0) offs[NKEY] = NE;
  if (i < 192) csr[NE + i] = 0;                    // zero pad for window prefetch
}

__global__ __launch_bounds__(256) void k_csr(
    const int* __restrict__ ei, const int* __restrict__ et,
    const int* __restrict__ offs, int* __restrict__ cnt, int* __restrict__ csr) {
  int e = blockIdx.x * 256 + threadIdx.x;
  if (e < NE) {
    int src = ei[e];
    int key = ei[NE + e] * NR + et[e];
    int old = atomicSub(&cnt[key], 1);
    csr[offs[key] + old - 1] = src;
  }
}

// ---- fused per-layer kernel -------------------------------------------------
// Block (512 thr, 8 waves) owns 32 dst nodes (74.2 KB LDS, 2 blocks/CU).
// Wave w owns 4 nodes = keys 32w..32w+31 (contiguous csr range).
// Changes vs the 16-node version (R1, 259 us):
//  * PING-PONG gather pipeline: issue-into-B/consume-A then issue-into-A/
//    consume-B — eliminates the nv->vb register copies whose pending-load
//    reads forced s_waitcnt vmcnt(0) every 8 edges (the structural drain that
//    made occupancy irrelevant). Consume waits are now vmcnt(15..8): >=8 loads
//    stay in flight per wave at all times.
//  * csr window double-buffer: pv0 is consumed, pv1 is a pure prefetch;
//    role-swap every 64 edges. pv1 is never read while in flight.
//  * 32 nodes/block: B-weight fragment loaded once feeds TWO row tiles ->
//    per-node L2 weight traffic halved (was 1.8 GB/dispatch chip-wide).
template <int RELU, int OUTBF>
__global__ __launch_bounds__(512, 4) void k_fused(
    const unsigned short* __restrict__ xb,   // [N][128] bf16
    const unsigned short* __restrict__ wl,   // [9][128][128] n-major bf16
    const int* __restrict__ offs, const int* __restrict__ csr,
    const float* __restrict__ bias, void* __restrict__ outp) {
  __shared__ unsigned int sAgg32[32 * RSTRIDE];    // [32 nodes][9*128+8] bf16, 74240 B
  const unsigned short* sAggH = (const unsigned short*)sAgg32;

  const int tid = threadIdx.x;
  const int w = tid >> 6;                          // 8 waves
  const int lane = tid & 63;
  const int m = lane & 15, q = lane >> 4;
  const int n0 = blockIdx.x * 32;
  const int k0 = n0 * NR;

  // this wave's 33 key offsets, one per lane (lane 0..32)
  int oidx = k0 + 32 * w + lane;
  if (oidx > NKEY) oidx = NKEY;
  const int offv = offs[oidx];
  const int p0 = __builtin_amdgcn_readlane(offv, 0);
  const int p1 = __builtin_amdgcn_readlane(offv, 32);

  // root row for this wave's 4 nodes: xb -> sAgg slot 8 (bf16 passthrough)
#pragma unroll
  for (int i = 0; i < 4; i++) {
    int node = 4 * w + i;
    unsigned int v = *(const unsigned int*)(xb + (size_t)(n0 + node) * DD + 2 * lane);
    sAgg32[node * RSTRIDE + 8 * 64 + lane] = v;
  }

  // ---- edge phase ----
  int kloc = 0;
  int kbeg = p0;
  int kend = __builtin_amdgcn_readlane(offv, 1);
  float ax = 0.f, ay = 0.f;

  // csr window: pv0 covers [wbase, wbase+64) and is the only one read;
  // pv1 covers [wbase+64, wbase+128) and is a prefetch, swapped in when
  // the read cursor crosses wbase+64 (its load is then 64 edges old).
  int wbase = p0;
  int pv0 = csr[wbase + lane];
  int pv1 = csr[wbase + 64 + lane];

#define ISSUE8(DST, NB) do {                                                 \
    if ((NB) - wbase == 64) {                                                \
      wbase += 64; pv0 = pv1; pv1 = csr[wbase + 64 + lane];                  \
    }                                                                        \
    const int ib_ = (NB) - wbase;                                            \
    _Pragma("unroll") for (int j_ = 0; j_ < 8; j_++) {                       \
      unsigned s_ = (unsigned)__builtin_amdgcn_readlane(pv0, ib_ + j_);      \
      (DST)[j_] = *(const ushort2*)(xb + (size_t)s_ * DD + 2 * lane);        \
    }                                                                        \
  } while (0)

#define CONSUME8(V, B0) do {                                                 \
    _Pragma("unroll") for (int j_ = 0; j_ < 8; j_++) {                       \
      if ((B0) + j_ < p1) {                                                  \
        while ((B0) + j_ >= kend) {                                          \
          float nm_ = __builtin_amdgcn_rcpf(fmaxf((float)(kend - kbeg), 1.f)); \
          unsigned lo_ = f2bf(ax * nm_), hi_ = f2bf(ay * nm_);               \
          int node_ = 4 * w + (kloc >> 3);                                   \
          sAgg32[node_ * RSTRIDE + (kloc & 7) * 64 + lane] = lo_ | (hi_ << 16); \
          ax = 0.f; ay = 0.f;                                                \
          kloc++;                                                            \
          kbeg = kend;                                                       \
          kend = __builtin_amdgcn_readlane(offv, kloc + 1);                  \
        }                                                                    \
        ax += bf2f((V)[j_].x);                                               \
        ay += bf2f((V)[j_].y);                                               \
      }                                                                      \
    }                                                                        \
  } while (0)

  ushort2 va[8], vb[8];
  ISSUE8(va, p0);                                  // prologue: edges p0..p0+7

  for (int base = p0; base < p1; base += 16) {
    ISSUE8(vb, base + 8);                          // issue edges base+8..+15
    CONSUME8(va, base);                            // consume edges base..+7
    ISSUE8(va, base + 16);                         // issue edges base+16..+23
    CONSUME8(vb, base + 8);                        // consume edges base+8..+15
  }
  // drain remaining keys (incl. empty)
  while (kloc < 32) {
    float nm = __builtin_amdgcn_rcpf(fmaxf((float)(kend - kbeg), 1.f));
    unsigned lo = f2bf(ax * nm), hi = f2bf(ay * nm);
    int node = 4 * w + (kloc >> 3);
    sAgg32[node * RSTRIDE + (kloc & 7) * 64 + lane] = lo | (hi << 16);
    ax = 0.f; ay = 0.f;
    kloc++;
    kbeg = kend;
    kend = (kloc < 32) ? __builtin_amdgcn_readlane(offv, kloc + 1) : kend;
  }
#undef ISSUE8
#undef CONSUME8
  __syncthreads();

  // ---- MFMA phase: wave w -> output cols 16w..16w+15, rows 0..31, 9 mats ----
  f32x4 acc0 = {0.f, 0.f, 0.f, 0.f};              // rows n0+0..15
  f32x4 acc1 = {0.f, 0.f, 0.f, 0.f};              // rows n0+16..31
  for (int mat = 0; mat < 9; mat++) {
    short8 a0[4], a1[4];
#pragma unroll
    for (int ks = 0; ks < 4; ks++) {
      a0[ks] = *(const short8*)(sAggH + m * (2 * RSTRIDE) + mat * 128 + ks * 32 + q * 8);
      a1[ks] = *(const short8*)(sAggH + (m + 16) * (2 * RSTRIDE) + mat * 128 + ks * 32 + q * 8);
    }
    const unsigned short* wr = wl + mat * DD * DD;
#pragma unroll
    for (int ks = 0; ks < 4; ks++) {
      short8 b = *(const short8*)(wr + (w * 16 + m) * DD + ks * 32 + q * 8);
      acc0 = __builtin_amdgcn_mfma_f32_16x16x32_bf16(a0[ks], b, acc0, 0, 0, 0);
      acc1 = __builtin_amdgcn_mfma_f32_16x16x32_bf16(a1[ks], b, acc1, 0, 0, 0);
    }
  }

  // epilogue: C/D row = q*4+i (+16 for acc1), col = w*16+m
  {
    const int c0 = w * 16 + m;
    const float bv = bias[c0];
#pragma unroll
    for (int i = 0; i < 4; i++) {
      int row0 = n0 + q * 4 + i;
      int row1 = row0 + 16;
      float v0 = acc0[i] + bv, v1 = acc1[i] + bv;
      if (RELU) { v0 = fmaxf(v0, 0.f); v1 = fmaxf(v1, 0.f); }
      if (OUTBF) {
        ((unsigned short*)outp)[(size_t)row0 * DD + c0] = f2bf(v0);
        ((unsigned short*)outp)[(size_t)row1 * DD + c0] = f2bf(v1);
      } else {
        ((float*)outp)[(size_t)row0 * DD + c0] = v0;
        ((float*)outp)[(size_t)row1 * DD + c0] = v1;
      }
    }
  }
}

// ---- launch -----------------------------------------------------------------

extern "C" void kernel_launch(void* const* d_in, const int* in_sizes, int n_in,
                              void* d_out, int out_size, void* d_ws, size_t ws_size,
                              hipStream_t stream) {
  const float* x     = (const float*)d_in[0];
  const int*   ei    = (const int*)d_in[1];
  const int*   et    = (const int*)d_in[2];
  const float* W1    = (const float*)d_in[3];
  const float* root1 = (const float*)d_in[4];
  const float* b1    = (const float*)d_in[5];
  const float* W2    = (const float*)d_in[6];
  const float* root2 = (const float*)d_in[7];
  const float* b2    = (const float*)d_in[8];
  float* out = (float*)d_out;

  char* p = (char*)d_ws;
  unsigned short* xb1 = (unsigned short*)p; p += (size_t)NN * DD * 2;   // 25.6 MB
  unsigned short* xb2 = (unsigned short*)p; p += (size_t)NN * DD * 2;   // 25.6 MB
  unsigned short* wbf = (unsigned short*)p; p += (size_t)2 * 9 * DD * DD * 2;
  int* cnt  = (int*)p; p += (size_t)NKEY * 4;                           // 3.2 MB
  int* offs = (int*)p; p += (size_t)(NKEY + 16) * 4;                    // 3.2 MB
  int* bsum = (int*)p; p += (size_t)800 * 4;                            // NBLK=782
  int* csr  = (int*)p; p += (size_t)(NE + 192) * 4;                     // 6.4 MB (+zeroed pad)
  // total ~= 64 MB

  k_cast<<<(NN * DD / 4 + 255) / 256, 256, 0, stream>>>(x, xb1);
  k_wtrans<<<(2 * 9 * 16384) / 256, 256, 0, stream>>>(W1, root1, W2, root2, wbf);
  k_zero<<<(NKEY + 255) / 256, 256, 0, stream>>>(cnt, NKEY);
  k_count<<<(NE + 255) / 256, 256, 0, stream>>>(ei, et, cnt);
  k_scan1<<<NBLK, 1024, 0, stream>>>(cnt, offs, bsum);
  k_scan2<<<1, 1024, 0, stream>>>(bsum);
  k_scan3<<<(NKEY + 255) / 256, 256, 0, stream>>>(offs, bsum, csr);
  k_csr<<<(NE + 255) / 256, 256, 0, stream>>>(ei, et, offs, cnt, csr);

  dim3 fgrid(NN / 32);   // 3125
  k_fused<1, 1><<<fgrid, 512, 0, stream>>>(xb1, wbf, offs, csr, b1, (void*)xb2);
  k_fused<0, 0><<<fgrid, 512, 0, stream>>>(xb2, wbf + 9 * DD * DD, offs, csr, b2, (void*)out);
}